// Round 1
// baseline (1529.773 us; speedup 1.0000x reference)
//
#include <hip/hip_runtime.h>

typedef __bf16 bf16x8 __attribute__((ext_vector_type(8)));
typedef float  f32x4  __attribute__((ext_vector_type(4)));

#define MFMA16(a,b,c) __builtin_amdgcn_mfma_f32_16x16x32_bf16((a),(b),(c),0,0,0)

constexpr int  HID  = 768;
constexpr long T    = 16384;          // NUM_SEQS * SEQ_LEN
constexpr long SZ   = T * HID;        // 12,582,912 elements
constexpr int  SEQ  = 2048;
constexpr int  NH   = 12;
constexpr int  HD   = 64;
constexpr int  WELE = HID * HID;      // 589,824

// ---------------------------------------------------------------------------
// Weight convert: Wt[n][k] = bf16(W[k][n])  (B^T layout for MFMA B-frag loads)
// ---------------------------------------------------------------------------
__global__ void wconv_kernel(const float* __restrict__ W, __bf16* __restrict__ Wt) {
    int idx = blockIdx.x * 256 + threadIdx.x;     // 0 .. WELE-1
    int n = idx / HID, k = idx % HID;
    Wt[idx] = (__bf16)W[k * HID + n];
}

// ---------------------------------------------------------------------------
// LayerNorm: x_bf16[row][:] = LN(hidden[row][:]) * w + b
// ---------------------------------------------------------------------------
__global__ __launch_bounds__(256)
void ln_kernel(const float* __restrict__ hs, const float* __restrict__ w,
               const float* __restrict__ b, __bf16* __restrict__ xbf) {
    int row = blockIdx.x, tid = threadIdx.x;
    const float* hr = hs + (long)row * HID;
    float v0 = hr[tid], v1 = hr[tid + 256], v2 = hr[tid + 512];
    float s  = v0 + v1 + v2;
    float s2 = v0 * v0 + v1 * v1 + v2 * v2;
#pragma unroll
    for (int off = 1; off < 64; off <<= 1) {
        s  += __shfl_xor(s, off);
        s2 += __shfl_xor(s2, off);
    }
    __shared__ float red[8];
    int wave = tid >> 6;
    if ((tid & 63) == 0) { red[wave] = s; red[4 + wave] = s2; }
    __syncthreads();
    s  = red[0] + red[1] + red[2] + red[3];
    s2 = red[4] + red[5] + red[6] + red[7];
    float mu   = s * (1.0f / HID);
    float var  = s2 * (1.0f / HID) - mu * mu;
    float rstd = rsqrtf(var + 1e-12f);
    long base = (long)row * HID;
    xbf[base + tid]       = (__bf16)((v0 - mu) * rstd * w[tid]       + b[tid]);
    xbf[base + tid + 256] = (__bf16)((v1 - mu) * rstd * w[tid + 256] + b[tid + 256]);
    xbf[base + tid + 512] = (__bf16)((v2 - mu) * rstd * w[tid + 512] + b[tid + 512]);
}

// ---------------------------------------------------------------------------
// GEMM: C[M=16384, N=768] = A[M,768] @ Bt^T + bias.  A bf16 row-major,
// Bt bf16 [N][K] (i.e. B^T).  64x64 block tile, 4 waves, each 16 rows x 64 cols.
// MODE 0: out bf16 [t][768]           (Q, K)
// MODE 1: out bf16 transposed per head: vt[((s*12+h)*64+d)*2048 + pos]  (V)
// MODE 2: out fp32 = acc + bias + resid(bf16)   (final proj + residual)
// ---------------------------------------------------------------------------
template <int MODE>
__global__ __launch_bounds__(256)
void gemm_bt(const __bf16* __restrict__ A, const __bf16* __restrict__ Bt,
             const float* __restrict__ bias, __bf16* __restrict__ outb,
             const __bf16* __restrict__ resid, float* __restrict__ outf) {
    int tid = threadIdx.x, wave = tid >> 6, lane = tid & 63;
    int lr = lane & 15, lk = (lane >> 4) * 8, q4 = (lane >> 4) * 4;
    long m0 = (long)blockIdx.x * 64 + wave * 16;   // wave's first row
    int  n0 = blockIdx.y * 64;
    f32x4 acc[4] = {{0,0,0,0},{0,0,0,0},{0,0,0,0},{0,0,0,0}};
    const __bf16* arow = A + (m0 + lr) * HID;
    for (int k0 = 0; k0 < HID; k0 += 32) {
        bf16x8 af = *(const bf16x8*)(arow + k0 + lk);
#pragma unroll
        for (int nc = 0; nc < 4; nc++) {
            bf16x8 bfr = *(const bf16x8*)(Bt + (long)(n0 + nc * 16 + lr) * HID + k0 + lk);
            acc[nc] = MFMA16(af, bfr, acc[nc]);
        }
    }
#pragma unroll
    for (int nc = 0; nc < 4; nc++) {
        int col = n0 + nc * 16 + lr;
        float bv = bias[col];
#pragma unroll
        for (int r = 0; r < 4; r++) {
            long row = m0 + q4 + r;
            float v = acc[nc][r] + bv;
            if (MODE == 0) {
                outb[row * HID + col] = (__bf16)v;
            } else if (MODE == 1) {
                int sq = (int)(row >> 11), pos = (int)(row & 2047);
                int hh = col >> 6, dd = col & 63;
                outb[((long)((sq * NH + hh) * HD + dd) << 11) + pos] = (__bf16)v;
            } else {
                outf[row * HID + col] = v + (float)resid[row * HID + col];
            }
        }
    }
}

// ---------------------------------------------------------------------------
// RoPE in place on q / k (blockIdx.y selects). pos = t % 2048, pairs (d, d+32).
// ---------------------------------------------------------------------------
__global__ __launch_bounds__(256)
void rope_kernel(__bf16* __restrict__ q, __bf16* __restrict__ k) {
    long idx = (long)blockIdx.x * 256 + threadIdx.x;   // over T * 12 * 32
    __bf16* arr = blockIdx.y ? k : q;
    int t = (int)(idx / 384);
    int r = (int)(idx % 384);
    int h = r >> 5, d = r & 31;
    int pos = t & (SEQ - 1);
    float freq = powf(10000.0f, -(float)d * (1.0f / 32.0f));
    float th = (float)pos * freq;
    float sn = sinf(th), cs = cosf(th);
    long base = (long)t * HID + h * HD + d;
    float x1 = (float)arr[base], x2 = (float)arr[base + 32];
    arr[base]      = (__bf16)(x1 * cs - x2 * sn);
    arr[base + 32] = (__bf16)(x2 * cs + x1 * sn);
}

// ---------------------------------------------------------------------------
// Flash attention: block = (64 q-rows, 1 head, 1 seq), 4 waves x 16 q-rows.
// Streams 32-key blocks: QK^T (4 MFMA) -> online softmax -> P through LDS
// -> PV (4 MFMA). vt layout [s][h][d][pos] makes V B-frags contiguous.
// ---------------------------------------------------------------------------
__global__ __launch_bounds__(256)
void attn_kernel(const __bf16* __restrict__ q, const __bf16* __restrict__ k,
                 const __bf16* __restrict__ vt, __bf16* __restrict__ att) {
    int tid = threadIdx.x, wave = tid >> 6, lane = tid & 63;
    int qt = blockIdx.x, h = blockIdx.y, s = blockIdx.z;
    int lr = lane & 15, lk = (lane >> 4) * 8, q4 = (lane >> 4) * 4;
    long q0 = (long)s * SEQ + qt * 64 + wave * 16;

    const __bf16* qrow = q + (q0 + lr) * HID + h * HD;
    bf16x8 qf0 = *(const bf16x8*)(qrow + lk);
    bf16x8 qf1 = *(const bf16x8*)(qrow + 32 + lk);

    f32x4 o0 = {0,0,0,0}, o1 = {0,0,0,0}, o2 = {0,0,0,0}, o3 = {0,0,0,0};
    float m_i[4] = {-INFINITY, -INFINITY, -INFINITY, -INFINITY};
    float l_i[4] = {0.f, 0.f, 0.f, 0.f};

    __shared__ __align__(16) __bf16 plds[4][16][48];   // 48 = 32 keys + pad

    const __bf16* kbase = k + (long)s * SEQ * HID + h * HD;
    const __bf16* vbase = vt + ((long)(s * NH + h) * HD) * SEQ;

    for (int kb = 0; kb < SEQ; kb += 32) {
        bf16x8 kf00 = *(const bf16x8*)(kbase + (long)(kb + lr) * HID + lk);
        bf16x8 kf01 = *(const bf16x8*)(kbase + (long)(kb + lr) * HID + 32 + lk);
        bf16x8 kf10 = *(const bf16x8*)(kbase + (long)(kb + 16 + lr) * HID + lk);
        bf16x8 kf11 = *(const bf16x8*)(kbase + (long)(kb + 16 + lr) * HID + 32 + lk);
        f32x4 s0 = {0,0,0,0}, s1 = {0,0,0,0};
        s0 = MFMA16(qf0, kf00, s0);
        s0 = MFMA16(qf1, kf01, s0);
        s1 = MFMA16(qf0, kf10, s1);
        s1 = MFMA16(qf1, kf11, s1);

        float alpha[4];
#pragma unroll
        for (int r = 0; r < 4; r++) {
            float a = s0[r] * 0.125f, bsc = s1[r] * 0.125f;
            float mx = fmaxf(a, bsc);
#pragma unroll
            for (int off = 1; off < 16; off <<= 1) mx = fmaxf(mx, __shfl_xor(mx, off));
            float nm = fmaxf(m_i[r], mx);
            alpha[r] = __expf(m_i[r] - nm);
            m_i[r] = nm;
            float e0 = __expf(a - nm), e1 = __expf(bsc - nm);
            float rs = e0 + e1;
#pragma unroll
            for (int off = 1; off < 16; off <<= 1) rs += __shfl_xor(rs, off);
            l_i[r] = l_i[r] * alpha[r] + rs;
            plds[wave][q4 + r][lr]      = (__bf16)e0;
            plds[wave][q4 + r][16 + lr] = (__bf16)e1;
        }
#pragma unroll
        for (int r = 0; r < 4; r++) {
            o0[r] *= alpha[r]; o1[r] *= alpha[r]; o2[r] *= alpha[r]; o3[r] *= alpha[r];
        }
        __syncthreads();   // P writes visible to A-frag reads (per-wave buffer)
        bf16x8 pa = *(const bf16x8*)&plds[wave][lr][lk];
        bf16x8 v0 = *(const bf16x8*)(vbase + (long)(0 * 16 + lr) * SEQ + kb + lk);
        bf16x8 v1 = *(const bf16x8*)(vbase + (long)(1 * 16 + lr) * SEQ + kb + lk);
        bf16x8 v2 = *(const bf16x8*)(vbase + (long)(2 * 16 + lr) * SEQ + kb + lk);
        bf16x8 v3 = *(const bf16x8*)(vbase + (long)(3 * 16 + lr) * SEQ + kb + lk);
        o0 = MFMA16(pa, v0, o0);
        o1 = MFMA16(pa, v1, o1);
        o2 = MFMA16(pa, v2, o2);
        o3 = MFMA16(pa, v3, o3);
        __syncthreads();   // keep waves off next-iter P writes until reads done
    }

#pragma unroll
    for (int r = 0; r < 4; r++) {
        float inv = 1.0f / l_i[r];
        long row = q0 + q4 + r;
        __bf16* ob = att + row * HID + h * HD;
        ob[0 * 16 + lr] = (__bf16)(o0[r] * inv);
        ob[1 * 16 + lr] = (__bf16)(o1[r] * inv);
        ob[2 * 16 + lr] = (__bf16)(o2[r] * inv);
        ob[3 * 16 + lr] = (__bf16)(o3[r] * inv);
    }
}

// ---------------------------------------------------------------------------
extern "C" void kernel_launch(void* const* d_in, const int* in_sizes, int n_in,
                              void* d_out, int out_size, void* d_ws, size_t ws_size,
                              hipStream_t stream) {
    const float* hs    = (const float*)d_in[0];
    const float* normw = (const float*)d_in[3];
    const float* normb = (const float*)d_in[4];
    const float* Wq = (const float*)d_in[5];
    const float* bq = (const float*)d_in[6];
    const float* Wk = (const float*)d_in[7];
    const float* bk = (const float*)d_in[8];
    const float* Wv = (const float*)d_in[9];
    const float* bv = (const float*)d_in[10];
    const float* Wo = (const float*)d_in[11];
    const float* bo = (const float*)d_in[12];

    __bf16* base = (__bf16*)d_ws;
    __bf16* x   = base;            // SZ
    __bf16* qb  = base + SZ;       // SZ
    __bf16* kb  = base + 2 * SZ;   // SZ
    __bf16* vtb = base + 3 * SZ;   // SZ  (transposed per head)
    __bf16* att = base + 4 * SZ;   // SZ
    __bf16* wqt = base + 5 * SZ;
    __bf16* wkt = wqt + WELE;
    __bf16* wvt = wkt + WELE;
    __bf16* wot = wvt + WELE;

    wconv_kernel<<<WELE / 256, 256, 0, stream>>>(Wq, wqt);
    wconv_kernel<<<WELE / 256, 256, 0, stream>>>(Wk, wkt);
    wconv_kernel<<<WELE / 256, 256, 0, stream>>>(Wv, wvt);
    wconv_kernel<<<WELE / 256, 256, 0, stream>>>(Wo, wot);

    ln_kernel<<<(int)T, 256, 0, stream>>>(hs, normw, normb, x);

    dim3 ggrid(T / 64, HID / 64);
    gemm_bt<0><<<ggrid, 256, 0, stream>>>(x, wqt, bq, qb, nullptr, nullptr);
    gemm_bt<0><<<ggrid, 256, 0, stream>>>(x, wkt, bk, kb, nullptr, nullptr);
    gemm_bt<1><<<ggrid, 256, 0, stream>>>(x, wvt, bv, vtb, nullptr, nullptr);

    rope_kernel<<<dim3((T * NH * 32) / 256, 2), 256, 0, stream>>>(qb, kb);

    attn_kernel<<<dim3(SEQ / 64, NH, 8), 256, 0, stream>>>(qb, kb, vtb, att);

    gemm_bt<2><<<ggrid, 256, 0, stream>>>(att, wot, bo, nullptr, x, (float*)d_out);
}

// Round 3
// 1450.767 us; speedup vs baseline: 1.0545x; 1.0545x over previous
//
#include <hip/hip_runtime.h>

typedef __bf16 bf16x8 __attribute__((ext_vector_type(8)));
typedef float  f32x4  __attribute__((ext_vector_type(4)));

#define MFMA16(a,b,c) __builtin_amdgcn_mfma_f32_16x16x32_bf16((a),(b),(c),0,0,0)

constexpr int  HID  = 768;
constexpr long T    = 16384;          // NUM_SEQS * SEQ_LEN
constexpr long SZ   = T * HID;        // 12,582,912 elements
constexpr int  SEQ  = 2048;
constexpr int  NH   = 12;
constexpr int  HD   = 64;
constexpr int  WELE = HID * HID;      // 589,824

// Q pre-scale: (1/sqrt(64)) * log2(e)  -> softmax done in exp2 domain
constexpr float QSCALE = 0.125f * 1.4426950408889634f;
// log2(10000)/32 for RoPE inv_freq = 2^(-d * L10K32)
constexpr float L10K32 = 13.287712379549449f / 32.0f;

// ---------------------------------------------------------------------------
// Weight convert+transpose, LDS-tiled (coalesced read AND write).
// blockIdx.z selects which of the 4 weights. Wt[n][k] = bf16(W[k][n]).
// ---------------------------------------------------------------------------
__global__ __launch_bounds__(256)
void wconv_kernel(const float* __restrict__ W0, __bf16* __restrict__ T0,
                  const float* __restrict__ W1, __bf16* __restrict__ T1,
                  const float* __restrict__ W2, __bf16* __restrict__ T2,
                  const float* __restrict__ W3, __bf16* __restrict__ T3) {
    const float* W; __bf16* Wt;
    switch (blockIdx.z) {
        case 0: W = W0; Wt = T0; break;
        case 1: W = W1; Wt = T1; break;
        case 2: W = W2; Wt = T2; break;
        default: W = W3; Wt = T3; break;
    }
    __shared__ float tile[64][65];
    int n0 = blockIdx.x * 64, k0 = blockIdx.y * 64;
    int c = threadIdx.x & 63, rr = threadIdx.x >> 6;
#pragma unroll
    for (int i = 0; i < 16; i++) {
        int r = i * 4 + rr;
        tile[r][c] = W[(long)(k0 + r) * HID + n0 + c];   // coalesced along n
    }
    __syncthreads();
#pragma unroll
    for (int i = 0; i < 16; i++) {
        int r = i * 4 + rr;                               // r = n index
        Wt[(long)(n0 + r) * HID + k0 + c] = (__bf16)tile[c][r];  // coalesced along k
    }
}

// ---------------------------------------------------------------------------
// LayerNorm: x_bf16[row][:] = LN(hidden[row][:]) * w + b
// ---------------------------------------------------------------------------
__global__ __launch_bounds__(256)
void ln_kernel(const float* __restrict__ hs, const float* __restrict__ w,
               const float* __restrict__ b, __bf16* __restrict__ xbf) {
    int row = blockIdx.x, tid = threadIdx.x;
    const float* hr = hs + (long)row * HID;
    float v0 = hr[tid], v1 = hr[tid + 256], v2 = hr[tid + 512];
    float s  = v0 + v1 + v2;
    float s2 = v0 * v0 + v1 * v1 + v2 * v2;
#pragma unroll
    for (int off = 1; off < 64; off <<= 1) {
        s  += __shfl_xor(s, off);
        s2 += __shfl_xor(s2, off);
    }
    __shared__ float red[8];
    int wave = tid >> 6;
    if ((tid & 63) == 0) { red[wave] = s; red[4 + wave] = s2; }
    __syncthreads();
    s  = red[0] + red[1] + red[2] + red[3];
    s2 = red[4] + red[5] + red[6] + red[7];
    float mu   = s * (1.0f / HID);
    float var  = s2 * (1.0f / HID) - mu * mu;
    float rstd = rsqrtf(var + 1e-12f);
    long base = (long)row * HID;
    xbf[base + tid]       = (__bf16)((v0 - mu) * rstd * w[tid]       + b[tid]);
    xbf[base + tid + 256] = (__bf16)((v1 - mu) * rstd * w[tid + 256] + b[tid + 256]);
    xbf[base + tid + 512] = (__bf16)((v2 - mu) * rstd * w[tid + 512] + b[tid + 512]);
}

// ---------------------------------------------------------------------------
// GEMM: C[M,N] = A[M,HID] @ Bt[N,HID]^T + bias.  64x64 block, 4 waves x 16 m.
// MODE 3: Q/K proj + fused RoPE (+ scale for Q). M=T, N=768, n0 = one head.
//         grid (T/64, 12).  out bf16 [t][768].
// MODE 1: V proj with A=Wv^T (M=768 d-dim), B=x (N=T pos-dim).
//         grid (12, T/64).  out bf16 vt[((s*12+h)*64+d)*2048 + pos], coalesced.
// MODE 2: final proj: out fp32 = acc + bias + resid(bf16).  grid (T/64, 12).
// ---------------------------------------------------------------------------
template <int MODE>
__global__ __launch_bounds__(256)
void gemm_bt(const __bf16* __restrict__ A, const __bf16* __restrict__ Bt,
             const float* __restrict__ bias, __bf16* __restrict__ outb,
             const __bf16* __restrict__ resid, float* __restrict__ outf,
             float scale) {
    int tid = threadIdx.x, wave = tid >> 6, lane = tid & 63;
    int lr = lane & 15, lk = (lane >> 4) * 8, q4 = (lane >> 4) * 4;
    long m0 = (long)blockIdx.x * 64 + wave * 16;   // wave's first output row
    int  n0 = blockIdx.y * 64;
    f32x4 acc[4] = {{0,0,0,0},{0,0,0,0},{0,0,0,0},{0,0,0,0}};
    const __bf16* arow = A + (m0 + lr) * HID;
    for (int k0 = 0; k0 < HID; k0 += 32) {
        bf16x8 af = *(const bf16x8*)(arow + k0 + lk);
#pragma unroll
        for (int nc = 0; nc < 4; nc++) {
            bf16x8 bfr = *(const bf16x8*)(Bt + (long)(n0 + nc * 16 + lr) * HID + k0 + lk);
            acc[nc] = MFMA16(af, bfr, acc[nc]);
        }
    }
    if (MODE == 3) {
        // RoPE pairs (d, d+32) are (acc[0],acc[2]) at d=lr and (acc[1],acc[3]) at d=lr+16
        float f1 = __builtin_amdgcn_exp2f(-(float)lr * L10K32);
        float f2 = __builtin_amdgcn_exp2f(-(float)(lr + 16) * L10K32);
        float b0 = bias[n0 + lr],      b1 = bias[n0 + 16 + lr];
        float b2 = bias[n0 + 32 + lr], b3 = bias[n0 + 48 + lr];
#pragma unroll
        for (int r = 0; r < 4; r++) {
            long row = m0 + q4 + r;
            int pos = (int)(row & (SEQ - 1));
            float s1, c1, s2, c2;
            __sincosf((float)pos * f1, &s1, &c1);
            __sincosf((float)pos * f2, &s2, &c2);
            float v0 = acc[0][r] + b0, v1 = acc[1][r] + b1;
            float v2 = acc[2][r] + b2, v3 = acc[3][r] + b3;
            __bf16* ob = outb + row * HID + n0;
            ob[lr]      = (__bf16)((v0 * c1 - v2 * s1) * scale);
            ob[16 + lr] = (__bf16)((v1 * c2 - v3 * s2) * scale);
            ob[32 + lr] = (__bf16)((v2 * c1 + v0 * s1) * scale);
            ob[48 + lr] = (__bf16)((v3 * c2 + v1 * s2) * scale);
        }
    } else if (MODE == 1) {
#pragma unroll
        for (int r = 0; r < 4; r++) {
            int d = (int)(m0 + q4 + r);          // global d in [0,768)
            float bv = bias[d];
            int hh = d >> 6, dd = d & 63;
#pragma unroll
            for (int nc = 0; nc < 4; nc++) {
                int posg = n0 + nc * 16 + lr;    // global token
                int sq = posg >> 11, pos = posg & (SEQ - 1);
                outb[((long)((sq * NH + hh) * HD + dd) << 11) + pos] =
                    (__bf16)(acc[nc][r] + bv);
            }
        }
    } else { // MODE 2
#pragma unroll
        for (int nc = 0; nc < 4; nc++) {
            int col = n0 + nc * 16 + lr;
            float bv = bias[col];
#pragma unroll
            for (int r = 0; r < 4; r++) {
                long row = m0 + q4 + r;
                outf[row * HID + col] = acc[nc][r] + bv + (float)resid[row * HID + col];
            }
        }
    }
}

// ---------------------------------------------------------------------------
// Flash attention, barrier-free. Block = 64 q-rows x 1 head x 1 seq; 4 waves
// each own 16 q-rows and a private double-buffered P tile in LDS.
// 128-key iterations: 16 QK MFMA -> softmax (exp2 domain) -> P via LDS
// (u16 scatter write, b128 read) -> 16 PV MFMA.  No __syncthreads at all.
// ---------------------------------------------------------------------------
__global__ __launch_bounds__(256)
void attn_kernel(const __bf16* __restrict__ q, const __bf16* __restrict__ k,
                 const __bf16* __restrict__ vt, __bf16* __restrict__ att) {
    int tid = threadIdx.x, wave = tid >> 6, lane = tid & 63;
    int qt = blockIdx.x, h = blockIdx.y, s = blockIdx.z;
    int lr = lane & 15, lk = (lane >> 4) * 8, q4 = (lane >> 4) * 4;
    long q0 = (long)s * SEQ + qt * 64 + wave * 16;

    const __bf16* qrow = q + (q0 + lr) * HID + h * HD;
    bf16x8 qf0 = *(const bf16x8*)(qrow + lk);
    bf16x8 qf1 = *(const bf16x8*)(qrow + 32 + lk);

    const f32x4 vzero = {0.f, 0.f, 0.f, 0.f};
    f32x4 o[4] = {vzero, vzero, vzero, vzero};
    float m_i[4] = {-INFINITY, -INFINITY, -INFINITY, -INFINITY};
    float l_i[4] = {0.f, 0.f, 0.f, 0.f};

    // 136 = 128 keys + 8 pad -> row stride 272B (16B-aligned, ≡4 banks mod 32:
    // b128 reads see only the free 2-way aliasing). Double-buffered per wave.
    __shared__ __align__(16) __bf16 plds[4][2][16][136];

    const __bf16* kbase = k + (long)s * SEQ * HID + h * HD;
    const __bf16* vbase = vt + ((long)(s * NH + h) * HD) * SEQ;

    int buf = 0;
    for (int kb = 0; kb < SEQ; kb += 128, buf ^= 1) {
        // ---- QK^T: 8 key-tiles of 16 ----
        f32x4 st[8];
#pragma unroll
        for (int j = 0; j < 8; j++) {
            const __bf16* krow = kbase + (long)(kb + j * 16 + lr) * HID;
            bf16x8 kf0 = *(const bf16x8*)(krow + lk);
            bf16x8 kf1 = *(const bf16x8*)(krow + 32 + lk);
            f32x4 sj = MFMA16(qf0, kf0, vzero);
            st[j] = MFMA16(qf1, kf1, sj);
        }
        // ---- online softmax (exp2 domain; Q pre-scaled by 1/8*log2e) ----
        float alpha[4];
#pragma unroll
        for (int r = 0; r < 4; r++) {
            float mx = st[0][r];
#pragma unroll
            for (int j = 1; j < 8; j++) mx = fmaxf(mx, st[j][r]);
#pragma unroll
            for (int off = 1; off < 16; off <<= 1) mx = fmaxf(mx, __shfl_xor(mx, off));
            float nm = fmaxf(m_i[r], mx);
            alpha[r] = __builtin_amdgcn_exp2f(m_i[r] - nm);
            m_i[r] = nm;
            float rs = 0.f;
#pragma unroll
            for (int j = 0; j < 8; j++) {
                float e = __builtin_amdgcn_exp2f(st[j][r] - nm);
                rs += e;
                plds[wave][buf][q4 + r][j * 16 + lr] = (__bf16)e;
            }
#pragma unroll
            for (int off = 1; off < 16; off <<= 1) rs += __shfl_xor(rs, off);
            l_i[r] = l_i[r] * alpha[r] + rs;
        }
#pragma unroll
        for (int r = 0; r < 4; r++) {
            o[0][r] *= alpha[r]; o[1][r] *= alpha[r];
            o[2][r] *= alpha[r]; o[3][r] *= alpha[r];
        }
        // wave-private LDS: only need this wave's writes visible to its reads
        asm volatile("s_waitcnt lgkmcnt(0)" ::: "memory");
        // ---- PV: 4 k-chunks of 32 ----
#pragma unroll
        for (int t = 0; t < 4; t++) {
            bf16x8 pa = *(const bf16x8*)&plds[wave][buf][lr][t * 32 + lk];
            const __bf16* vb = vbase + kb + t * 32 + lk;
#pragma unroll
            for (int d16 = 0; d16 < 4; d16++) {
                bf16x8 vf = *(const bf16x8*)(vb + (long)(d16 * 16 + lr) * SEQ);
                o[d16] = MFMA16(pa, vf, o[d16]);
            }
        }
    }

#pragma unroll
    for (int r = 0; r < 4; r++) {
        float inv = 1.0f / l_i[r];
        long row = q0 + q4 + r;
        __bf16* ob = att + row * HID + h * HD;
        ob[0 * 16 + lr] = (__bf16)(o[0][r] * inv);
        ob[1 * 16 + lr] = (__bf16)(o[1][r] * inv);
        ob[2 * 16 + lr] = (__bf16)(o[2][r] * inv);
        ob[3 * 16 + lr] = (__bf16)(o[3][r] * inv);
    }
}

// ---------------------------------------------------------------------------
extern "C" void kernel_launch(void* const* d_in, const int* in_sizes, int n_in,
                              void* d_out, int out_size, void* d_ws, size_t ws_size,
                              hipStream_t stream) {
    const float* hs    = (const float*)d_in[0];
    const float* normw = (const float*)d_in[3];
    const float* normb = (const float*)d_in[4];
    const float* Wq = (const float*)d_in[5];
    const float* bq = (const float*)d_in[6];
    const float* Wk = (const float*)d_in[7];
    const float* bk = (const float*)d_in[8];
    const float* Wv = (const float*)d_in[9];
    const float* bv = (const float*)d_in[10];
    const float* Wo = (const float*)d_in[11];
    const float* bo = (const float*)d_in[12];

    __bf16* base = (__bf16*)d_ws;
    __bf16* x   = base;            // SZ
    __bf16* qb  = base + SZ;       // SZ
    __bf16* kb  = base + 2 * SZ;   // SZ
    __bf16* vtb = base + 3 * SZ;   // SZ  (transposed per head: [s][h][d][pos])
    __bf16* att = base + 4 * SZ;   // SZ
    __bf16* wqt = base + 5 * SZ;
    __bf16* wkt = wqt + WELE;
    __bf16* wvt = wkt + WELE;
    __bf16* wot = wvt + WELE;

    wconv_kernel<<<dim3(12, 12, 4), 256, 0, stream>>>(Wq, wqt, Wk, wkt, Wv, wvt, Wo, wot);

    ln_kernel<<<(int)T, 256, 0, stream>>>(hs, normw, normb, x);

    // Q, K projections with fused RoPE (Q also folds 1/8*log2e)
    gemm_bt<3><<<dim3(T / 64, HID / 64), 256, 0, stream>>>(x, wqt, bq, qb, nullptr, nullptr, QSCALE);
    gemm_bt<3><<<dim3(T / 64, HID / 64), 256, 0, stream>>>(x, wkt, bk, kb, nullptr, nullptr, 1.0f);
    // V projection, transposed output (A = Wv^T, B = x)
    gemm_bt<1><<<dim3(HID / 64, T / 64), 256, 0, stream>>>(wvt, x, bv, vtb, nullptr, nullptr, 1.0f);

    attn_kernel<<<dim3(SEQ / 64, NH, 8), 256, 0, stream>>>(qb, kb, vtb, att);

    gemm_bt<2><<<dim3(T / 64, HID / 64), 256, 0, stream>>>(att, wot, bo, nullptr, x, (float*)d_out, 1.0f);
}

// Round 4
// 1449.536 us; speedup vs baseline: 1.0554x; 1.0008x over previous
//
#include <hip/hip_runtime.h>

typedef __bf16 bf16x8 __attribute__((ext_vector_type(8)));
typedef float  f32x4  __attribute__((ext_vector_type(4)));

#define MFMA16(a,b,c) __builtin_amdgcn_mfma_f32_16x16x32_bf16((a),(b),(c),0,0,0)

constexpr int  HID  = 768;
constexpr long T    = 16384;          // NUM_SEQS * SEQ_LEN
constexpr long SZ   = T * HID;        // 12,582,912 elements
constexpr int  SEQ  = 2048;
constexpr int  NH   = 12;
constexpr int  HD   = 64;
constexpr int  WELE = HID * HID;      // 589,824

// Q pre-scale: (1/sqrt(64)) * log2(e)  -> softmax done in exp2 domain
constexpr float QSCALE = 0.125f * 1.4426950408889634f;
// log2(10000)/32 for RoPE inv_freq = 2^(-d * L10K32)
constexpr float L10K32 = 13.287712379549449f / 32.0f;

// ---------------------------------------------------------------------------
// Weight convert+transpose, LDS-tiled (coalesced read AND write).
// blockIdx.z selects which of the 4 weights. Wt[n][k] = bf16(W[k][n]).
// ---------------------------------------------------------------------------
__global__ __launch_bounds__(256)
void wconv_kernel(const float* __restrict__ W0, __bf16* __restrict__ T0,
                  const float* __restrict__ W1, __bf16* __restrict__ T1,
                  const float* __restrict__ W2, __bf16* __restrict__ T2,
                  const float* __restrict__ W3, __bf16* __restrict__ T3) {
    const float* W; __bf16* Wt;
    switch (blockIdx.z) {
        case 0: W = W0; Wt = T0; break;
        case 1: W = W1; Wt = T1; break;
        case 2: W = W2; Wt = T2; break;
        default: W = W3; Wt = T3; break;
    }
    __shared__ float tile[64][65];
    int n0 = blockIdx.x * 64, k0 = blockIdx.y * 64;
    int c = threadIdx.x & 63, rr = threadIdx.x >> 6;
#pragma unroll
    for (int i = 0; i < 16; i++) {
        int r = i * 4 + rr;
        tile[r][c] = W[(long)(k0 + r) * HID + n0 + c];   // coalesced along n
    }
    __syncthreads();
#pragma unroll
    for (int i = 0; i < 16; i++) {
        int r = i * 4 + rr;                               // r = n index
        Wt[(long)(n0 + r) * HID + k0 + c] = (__bf16)tile[c][r];  // coalesced along k
    }
}

// ---------------------------------------------------------------------------
// LayerNorm: x_bf16[row][:] = LN(hidden[row][:]) * w + b
// ---------------------------------------------------------------------------
__global__ __launch_bounds__(256)
void ln_kernel(const float* __restrict__ hs, const float* __restrict__ w,
               const float* __restrict__ b, __bf16* __restrict__ xbf) {
    int row = blockIdx.x, tid = threadIdx.x;
    const float* hr = hs + (long)row * HID;
    float v0 = hr[tid], v1 = hr[tid + 256], v2 = hr[tid + 512];
    float s  = v0 + v1 + v2;
    float s2 = v0 * v0 + v1 * v1 + v2 * v2;
#pragma unroll
    for (int off = 1; off < 64; off <<= 1) {
        s  += __shfl_xor(s, off);
        s2 += __shfl_xor(s2, off);
    }
    __shared__ float red[8];
    int wave = tid >> 6;
    if ((tid & 63) == 0) { red[wave] = s; red[4 + wave] = s2; }
    __syncthreads();
    s  = red[0] + red[1] + red[2] + red[3];
    s2 = red[4] + red[5] + red[6] + red[7];
    float mu   = s * (1.0f / HID);
    float var  = s2 * (1.0f / HID) - mu * mu;
    float rstd = rsqrtf(var + 1e-12f);
    long base = (long)row * HID;
    xbf[base + tid]       = (__bf16)((v0 - mu) * rstd * w[tid]       + b[tid]);
    xbf[base + tid + 256] = (__bf16)((v1 - mu) * rstd * w[tid + 256] + b[tid + 256]);
    xbf[base + tid + 512] = (__bf16)((v2 - mu) * rstd * w[tid + 512] + b[tid + 512]);
}

// ---------------------------------------------------------------------------
// GEMM: C[M,N] = A[M,HID] @ Bt[N,HID]^T + bias.  64x64 block, 4 waves x 16 m.
// MODE 3: Q/K proj + fused RoPE (+ scale for Q). grid (T/64, 12).
// MODE 1: V proj with A=Wv^T (M=768 d-dim), B=x (N=T pos-dim). grid (12, T/64).
//         out bf16 vt[((s*12+h)*64+d)*2048 + pos], coalesced.
// MODE 2: final proj: out fp32 = acc + bias + resid(bf16).  grid (T/64, 12).
// ---------------------------------------------------------------------------
template <int MODE>
__global__ __launch_bounds__(256)
void gemm_bt(const __bf16* __restrict__ A, const __bf16* __restrict__ Bt,
             const float* __restrict__ bias, __bf16* __restrict__ outb,
             const __bf16* __restrict__ resid, float* __restrict__ outf,
             float scale) {
    int tid = threadIdx.x, wave = tid >> 6, lane = tid & 63;
    int lr = lane & 15, lk = (lane >> 4) * 8, q4 = (lane >> 4) * 4;
    long m0 = (long)blockIdx.x * 64 + wave * 16;   // wave's first output row
    int  n0 = blockIdx.y * 64;
    f32x4 acc[4] = {{0,0,0,0},{0,0,0,0},{0,0,0,0},{0,0,0,0}};
    const __bf16* arow = A + (m0 + lr) * HID;
    for (int k0 = 0; k0 < HID; k0 += 32) {
        bf16x8 af = *(const bf16x8*)(arow + k0 + lk);
#pragma unroll
        for (int nc = 0; nc < 4; nc++) {
            bf16x8 bfr = *(const bf16x8*)(Bt + (long)(n0 + nc * 16 + lr) * HID + k0 + lk);
            acc[nc] = MFMA16(af, bfr, acc[nc]);
        }
    }
    if (MODE == 3) {
        // RoPE pairs (d, d+32) are (acc[0],acc[2]) at d=lr and (acc[1],acc[3]) at d=lr+16
        float f1 = __builtin_amdgcn_exp2f(-(float)lr * L10K32);
        float f2 = __builtin_amdgcn_exp2f(-(float)(lr + 16) * L10K32);
        float b0 = bias[n0 + lr],      b1 = bias[n0 + 16 + lr];
        float b2 = bias[n0 + 32 + lr], b3 = bias[n0 + 48 + lr];
#pragma unroll
        for (int r = 0; r < 4; r++) {
            long row = m0 + q4 + r;
            int pos = (int)(row & (SEQ - 1));
            float s1, c1, s2, c2;
            __sincosf((float)pos * f1, &s1, &c1);
            __sincosf((float)pos * f2, &s2, &c2);
            float v0 = acc[0][r] + b0, v1 = acc[1][r] + b1;
            float v2 = acc[2][r] + b2, v3 = acc[3][r] + b3;
            __bf16* ob = outb + row * HID + n0;
            ob[lr]      = (__bf16)((v0 * c1 - v2 * s1) * scale);
            ob[16 + lr] = (__bf16)((v1 * c2 - v3 * s2) * scale);
            ob[32 + lr] = (__bf16)((v2 * c1 + v0 * s1) * scale);
            ob[48 + lr] = (__bf16)((v3 * c2 + v1 * s2) * scale);
        }
    } else if (MODE == 1) {
#pragma unroll
        for (int r = 0; r < 4; r++) {
            int d = (int)(m0 + q4 + r);          // global d in [0,768)
            float bv = bias[d];
            int hh = d >> 6, dd = d & 63;
#pragma unroll
            for (int nc = 0; nc < 4; nc++) {
                int posg = n0 + nc * 16 + lr;    // global token
                int sq = posg >> 11, pos = posg & (SEQ - 1);
                outb[((long)((sq * NH + hh) * HD + dd) << 11) + pos] =
                    (__bf16)(acc[nc][r] + bv);
            }
        }
    } else { // MODE 2
#pragma unroll
        for (int nc = 0; nc < 4; nc++) {
            int col = n0 + nc * 16 + lr;
            float bv = bias[col];
#pragma unroll
            for (int r = 0; r < 4; r++) {
                long row = m0 + q4 + r;
                outf[row * HID + col] = acc[nc][r] + bv + (float)resid[row * HID + col];
            }
        }
    }
}

// ---------------------------------------------------------------------------
// Flash attention, barrier-free. Block = 64 q-rows x 1 head x 1 seq; 4 waves
// each own 16 q-rows and a private P tile in LDS (single-buffered: in-order
// wave execution makes WAR across iterations safe — PV reads land in regs
// before the MFMA issues, which precedes next-iter ds_writes).
// Row stride 144 elems (288B = 8 banks mod 32): u16 P-scatter is exactly
// 2 lanes/bank (free); b128 reads clean.  LDS 18.4KB -> 8 blocks/CU.
// l_i kept as per-lane partials; one 16-lane reduction in the epilogue.
// ---------------------------------------------------------------------------
__global__ __launch_bounds__(256)
void attn_kernel(const __bf16* __restrict__ q, const __bf16* __restrict__ k,
                 const __bf16* __restrict__ vt, __bf16* __restrict__ att) {
    int tid = threadIdx.x, wave = tid >> 6, lane = tid & 63;
    int qt = blockIdx.x, h = blockIdx.y, s = blockIdx.z;
    int lr = lane & 15, lk = (lane >> 4) * 8, q4 = (lane >> 4) * 4;
    long q0 = (long)s * SEQ + qt * 64 + wave * 16;

    const __bf16* qrow = q + (q0 + lr) * HID + h * HD;
    bf16x8 qf0 = *(const bf16x8*)(qrow + lk);
    bf16x8 qf1 = *(const bf16x8*)(qrow + 32 + lk);

    const f32x4 vzero = {0.f, 0.f, 0.f, 0.f};
    f32x4 o[4] = {vzero, vzero, vzero, vzero};
    float m_i[4]  = {-INFINITY, -INFINITY, -INFINITY, -INFINITY};
    float lsum[4] = {0.f, 0.f, 0.f, 0.f};   // per-lane partial (8 cols each)

    __shared__ __align__(16) __bf16 plds[4][16][144];

    const __bf16* kbase = k + (long)s * SEQ * HID + h * HD;
    const __bf16* vbase = vt + ((long)(s * NH + h) * HD) * SEQ;

    for (int kb = 0; kb < SEQ; kb += 128) {
        // ---- QK^T: 8 key-tiles of 16 ----
        f32x4 st[8];
#pragma unroll
        for (int j = 0; j < 8; j++) {
            const __bf16* krow = kbase + (long)(kb + j * 16 + lr) * HID;
            bf16x8 kf0 = *(const bf16x8*)(krow + lk);
            bf16x8 kf1 = *(const bf16x8*)(krow + 32 + lk);
            f32x4 sj = MFMA16(qf0, kf0, vzero);
            st[j] = MFMA16(qf1, kf1, sj);
        }
        // ---- online softmax (exp2 domain; Q pre-scaled by 1/8*log2e) ----
        float alpha[4];
#pragma unroll
        for (int r = 0; r < 4; r++) {
            float mx = st[0][r];
#pragma unroll
            for (int j = 1; j < 8; j++) mx = fmaxf(mx, st[j][r]);
#pragma unroll
            for (int off = 1; off < 16; off <<= 1) mx = fmaxf(mx, __shfl_xor(mx, off));
            float nm = fmaxf(m_i[r], mx);
            alpha[r] = __builtin_amdgcn_exp2f(m_i[r] - nm);
            m_i[r] = nm;
            float rs = 0.f;
#pragma unroll
            for (int j = 0; j < 8; j++) {
                float e = __builtin_amdgcn_exp2f(st[j][r] - nm);
                rs += e;
                plds[wave][q4 + r][j * 16 + lr] = (__bf16)e;
            }
            lsum[r] = lsum[r] * alpha[r] + rs;   // lane-local; reduce at end
        }
#pragma unroll
        for (int r = 0; r < 4; r++) {
            o[0][r] *= alpha[r]; o[1][r] *= alpha[r];
            o[2][r] *= alpha[r]; o[3][r] *= alpha[r];
        }
        // wave-private LDS: only need this wave's writes visible to its reads
        asm volatile("s_waitcnt lgkmcnt(0)" ::: "memory");
        // ---- PV: 4 k-chunks of 32 ----
#pragma unroll
        for (int t = 0; t < 4; t++) {
            bf16x8 pa = *(const bf16x8*)&plds[wave][lr][t * 32 + lk];
            const __bf16* vb = vbase + kb + t * 32 + lk;
#pragma unroll
            for (int d16 = 0; d16 < 4; d16++) {
                bf16x8 vf = *(const bf16x8*)(vb + (long)(d16 * 16 + lr) * SEQ);
                o[d16] = MFMA16(pa, vf, o[d16]);
            }
        }
    }

#pragma unroll
    for (int r = 0; r < 4; r++) {
        float l = lsum[r];
#pragma unroll
        for (int off = 1; off < 16; off <<= 1) l += __shfl_xor(l, off);
        float inv = 1.0f / l;
        long row = q0 + q4 + r;
        __bf16* ob = att + row * HID + h * HD;
        ob[0 * 16 + lr] = (__bf16)(o[0][r] * inv);
        ob[1 * 16 + lr] = (__bf16)(o[1][r] * inv);
        ob[2 * 16 + lr] = (__bf16)(o[2][r] * inv);
        ob[3 * 16 + lr] = (__bf16)(o[3][r] * inv);
    }
}

// ---------------------------------------------------------------------------
extern "C" void kernel_launch(void* const* d_in, const int* in_sizes, int n_in,
                              void* d_out, int out_size, void* d_ws, size_t ws_size,
                              hipStream_t stream) {
    const float* hs    = (const float*)d_in[0];
    const float* normw = (const float*)d_in[3];
    const float* normb = (const float*)d_in[4];
    const float* Wq = (const float*)d_in[5];
    const float* bq = (const float*)d_in[6];
    const float* Wk = (const float*)d_in[7];
    const float* bk = (const float*)d_in[8];
    const float* Wv = (const float*)d_in[9];
    const float* bv = (const float*)d_in[10];
    const float* Wo = (const float*)d_in[11];
    const float* bo = (const float*)d_in[12];

    __bf16* base = (__bf16*)d_ws;
    __bf16* x   = base;            // SZ
    __bf16* qb  = base + SZ;       // SZ
    __bf16* kb  = base + 2 * SZ;   // SZ
    __bf16* vtb = base + 3 * SZ;   // SZ  (transposed per head: [s][h][d][pos])
    __bf16* att = base + 4 * SZ;   // SZ
    __bf16* wqt = base + 5 * SZ;
    __bf16* wkt = wqt + WELE;
    __bf16* wvt = wkt + WELE;
    __bf16* wot = wvt + WELE;

    wconv_kernel<<<dim3(12, 12, 4), 256, 0, stream>>>(Wq, wqt, Wk, wkt, Wv, wvt, Wo, wot);

    ln_kernel<<<(int)T, 256, 0, stream>>>(hs, normw, normb, x);

    // Q, K projections with fused RoPE (Q also folds 1/8*log2e)
    gemm_bt<3><<<dim3(T / 64, HID / 64), 256, 0, stream>>>(x, wqt, bq, qb, nullptr, nullptr, QSCALE);
    gemm_bt<3><<<dim3(T / 64, HID / 64), 256, 0, stream>>>(x, wkt, bk, kb, nullptr, nullptr, 1.0f);
    // V projection, transposed output (A = Wv^T, B = x)
    gemm_bt<1><<<dim3(HID / 64, T / 64), 256, 0, stream>>>(wvt, x, bv, vtb, nullptr, nullptr, 1.0f);

    attn_kernel<<<dim3(SEQ / 64, NH, 8), 256, 0, stream>>>(qb, kb, vtb, att);

    gemm_bt<2><<<dim3(T / 64, HID / 64), 256, 0, stream>>>(att, wot, bo, nullptr, x, (float*)d_out, 1.0f);
}